// Round 1
// baseline (197.112 us; speedup 1.0000x reference)
//
#include <hip/hip_runtime.h>

#define Mpts 32768
#define Vv 9
#define Cc 24
#define Hh 120
#define Ww 160
#define Npts (Mpts * 8)          // 262144
#define PIX (Hh * Ww)            // 19200
#define VOXEL 0.04f

// ---------------- workspace layout (bytes) ----------------
// [0,32)               : 3 doubles: sum_z, sum_z2, pos_cnt
// [32, +16588800)      : tf   = transposed feats (V,H,W,C) f32
// then pre_h  (M,24) f32      : 3145728 B
// then hpartT (24,N)  f32     : 25165824 B
// then zbuf   (N)     f32     : 1048576 B
#define OFF_TF    32
#define OFF_PREH  (OFF_TF + Vv * PIX * Cc * 4)          // 32 + 16588800
#define OFF_HP    (OFF_PREH + Mpts * Cc * 4)
#define OFF_Z     (OFF_HP + Cc * Npts * 4)

// ---------------- 1) transpose feats (V,C,H,W) -> (V,H,W,C) ----------------
__global__ __launch_bounds__(256) void transpose_feats(
    const float* __restrict__ feats, float* __restrict__ tf) {
  __shared__ float tile[64][Cc + 1];
  int blk = blockIdx.x;               // v*300 + tile
  int v = blk / (PIX / 64);
  int p0 = (blk % (PIX / 64)) * 64;
  const float* src = feats + v * (Cc * PIX);
  for (int i = threadIdx.x; i < Cc * 64; i += 256) {
    int c = i >> 6;                   // /64
    int p = i & 63;
    tile[p][c] = src[c * PIX + p0 + p];
  }
  __syncthreads();
  float* dst = tf + v * (PIX * Cc);
  for (int i = threadIdx.x; i < Cc * 64; i += 256) {
    int p = i / Cc;
    int c = i - p * Cc;
    dst[(p0 + p) * Cc + c] = tile[p][c];
  }
}

// ---------------- 2) pre_h[m,:] = b_sp + pre_feat[m,:] @ W_sp[25:75,:] ------
__global__ __launch_bounds__(256) void pre_h_kernel(
    const float* __restrict__ pre_feat, const float* __restrict__ W_sp,
    const float* __restrict__ b_sp, float* __restrict__ pre_h) {
  __shared__ float Wl[50 * Cc];
  __shared__ float bl[Cc];
  for (int i = threadIdx.x; i < 50 * Cc; i += 256) Wl[i] = W_sp[25 * Cc + i];
  if (threadIdx.x < Cc) bl[threadIdx.x] = b_sp[threadIdx.x];
  __syncthreads();
  int m = blockIdx.x * 256 + threadIdx.x;
  float acc[Cc];
#pragma unroll
  for (int j = 0; j < Cc; j++) acc[j] = bl[j];
  const float* pf = pre_feat + m * 50;
  for (int k = 0; k < 50; k++) {
    float x = pf[k];
#pragma unroll
    for (int j = 0; j < Cc; j++) acc[j] += x * Wl[k * Cc + j];
  }
  float* o = pre_h + m * Cc;
#pragma unroll
  for (int j = 0; j < Cc; j++) o[j] = acc[j];
}

// ---------------- 3) main: project + sample + partial h + reduction --------
__global__ __launch_bounds__(256) void main_kernel(
    const int* __restrict__ pre_coords, const float* __restrict__ tf,
    const float* __restrict__ KRcam, const float* __restrict__ vol_origin,
    const float* __restrict__ w2ac, const float* __restrict__ W_sp,
    const float* __restrict__ pre_h, float* __restrict__ out,
    float* __restrict__ hpartT, float* __restrict__ zbuf,
    double* __restrict__ red) {
  __shared__ float KR[Vv * 12];
  __shared__ float Wl[Cc * Cc];      // W_sp[0:24,:]
  __shared__ float w2a[12];
  __shared__ float orig[3];
  __shared__ float redl[3][4];
  for (int i = threadIdx.x; i < Vv * 12; i += 256) {
    int v = i / 12, r = i - v * 12;
    KR[i] = KRcam[v * 16 + r];
  }
  for (int i = threadIdx.x; i < Cc * Cc; i += 256) Wl[i] = W_sp[i];
  if (threadIdx.x < 12) w2a[threadIdx.x] = w2ac[threadIdx.x];
  if (threadIdx.x < 3) orig[threadIdx.x] = vol_origin[threadIdx.x];
  __syncthreads();

  int n = blockIdx.x * 256 + threadIdx.x;   // grid covers exactly Npts
  int m = n >> 3, o = n & 7;
  int cx = pre_coords[m * 4 + 1] + ((0xB2 >> o) & 1);
  int cy = pre_coords[m * 4 + 2] + ((0xD4 >> o) & 1);
  int cz = pre_coords[m * 4 + 3] + ((0xE8 >> o) & 1);
  float wx0 = (float)cx * VOXEL + orig[0];
  float wy0 = (float)cy * VOXEL + orig[1];
  float wz0 = (float)cz * VOXEL + orig[2];

  // r_coords
  {
    float camx = w2a[0] * wx0 + w2a[1] * wy0 + w2a[2] * wz0 + w2a[3];
    float camy = w2a[4] * wx0 + w2a[5] * wy0 + w2a[6] * wz0 + w2a[7];
    float camz = w2a[8] * wx0 + w2a[9] * wy0 + w2a[10] * wz0 + w2a[11];
    float4 rc = make_float4(camx, camy, camz, (float)pre_coords[m * 4 + 0]);
    ((float4*)(out + 3 * Npts))[n] = rc;
  }

  float4 acc[6];
#pragma unroll
  for (int q = 0; q < 6; q++) acc[q] = make_float4(0.f, 0.f, 0.f, 0.f);
  float zsum = 0.f;
  int cnt = 0;

  for (int v = 0; v < Vv; v++) {
    const float* kr = &KR[v * 12];
    float ix = kr[0] * wx0 + kr[1] * wy0 + kr[2] * wz0 + kr[3];
    float iy = kr[4] * wx0 + kr[5] * wy0 + kr[6] * wz0 + kr[7];
    float iz = kr[8] * wx0 + kr[9] * wy0 + kr[10] * wz0 + kr[11];
    float sz = (fabsf(iz) > 1e-9f) ? iz : 1e-9f;
    float px = ix / sz;
    float py = iy / sz;
    bool msk = (px >= 0.f) && (px <= (float)(Ww - 1)) && (py >= 0.f) &&
               (py <= (float)(Hh - 1)) && (iz > 0.f);
    if (msk) {
      float fx0 = floorf(px), fy0 = floorf(py);
      float wx = px - fx0, wy = py - fy0;
      int x0 = (int)fx0, y0 = (int)fy0;
      int x1 = min(x0 + 1, Ww - 1), y1 = min(y0 + 1, Hh - 1);
      float w00 = (1.f - wx) * (1.f - wy);
      float w10 = wx * (1.f - wy);
      float w01 = (1.f - wx) * wy;
      float w11 = wx * wy;
      const float* base = tf + v * (PIX * Cc);
      const float4* p00 = (const float4*)(base + (y0 * Ww + x0) * Cc);
      const float4* p10 = (const float4*)(base + (y0 * Ww + x1) * Cc);
      const float4* p01 = (const float4*)(base + (y1 * Ww + x0) * Cc);
      const float4* p11 = (const float4*)(base + (y1 * Ww + x1) * Cc);
#pragma unroll
      for (int q = 0; q < 6; q++) {
        float4 a = p00[q], b = p10[q], c = p01[q], d = p11[q];
        acc[q].x += w00 * a.x + w10 * b.x + w01 * c.x + w11 * d.x;
        acc[q].y += w00 * a.y + w10 * b.y + w01 * c.y + w11 * d.y;
        acc[q].z += w00 * a.z + w10 * b.z + w01 * c.z + w11 * d.z;
        acc[q].w += w00 * a.w + w10 * b.w + w01 * c.w + w11 * d.w;
      }
      zsum += iz;
      cnt++;
    }
  }

  float denom = fmaxf((float)cnt, 1.f);
  float invd = 1.f / denom;
  float z = zsum * invd;

  // features into acc (reuse regs)
  float feat[Cc];
#pragma unroll
  for (int q = 0; q < 6; q++) {
    feat[q * 4 + 0] = acc[q].x * invd;
    feat[q * 4 + 1] = acc[q].y * invd;
    feat[q * 4 + 2] = acc[q].z * invd;
    feat[q * 4 + 3] = acc[q].w * invd;
  }

  // hpart = pre_h[m] + features @ W_sp[0:24,:]
  float h[Cc];
  const float* ph = pre_h + m * Cc;
#pragma unroll
  for (int j = 0; j < Cc; j++) h[j] = ph[j];
  for (int c = 0; c < Cc; c++) {
    float f = feat[c];
#pragma unroll
    for (int j = 0; j < Cc; j++) h[j] += f * Wl[c * Cc + j];
  }
#pragma unroll
  for (int j = 0; j < Cc; j++) hpartT[j * Npts + n] = h[j];

  zbuf[n] = z;
  out[2 * Npts + n] = (float)cnt;   // count output

  // reduction for zmean / znorm
  float rz = (z > 0.f) ? z : 0.f;
  float rz2 = rz * rz;
  float rcn = (z > 0.f) ? 1.f : 0.f;
#pragma unroll
  for (int off = 32; off > 0; off >>= 1) {
    rz += __shfl_down(rz, off);
    rz2 += __shfl_down(rz2, off);
    rcn += __shfl_down(rcn, off);
  }
  int wid = threadIdx.x >> 6, lid = threadIdx.x & 63;
  if (lid == 0) {
    redl[0][wid] = rz;
    redl[1][wid] = rz2;
    redl[2][wid] = rcn;
  }
  __syncthreads();
  if (threadIdx.x == 0) {
    float a = 0.f, b = 0.f, c = 0.f;
#pragma unroll
    for (int w = 0; w < 4; w++) {
      a += redl[0][w];
      b += redl[1][w];
      c += redl[2][w];
    }
    atomicAdd(&red[0], (double)a);
    atomicAdd(&red[1], (double)b);
    atomicAdd(&red[2], (double)c);
  }
}

// ---------------- 4) finalize: zn + relu + heads ---------------------------
__global__ __launch_bounds__(256) void final_kernel(
    const float* __restrict__ zbuf, const float* __restrict__ hpartT,
    const float* __restrict__ W_sp, const float* __restrict__ W_t,
    const float* __restrict__ b_t, const float* __restrict__ W_o,
    const float* __restrict__ b_o, const double* __restrict__ red,
    float* __restrict__ out) {
  __shared__ float wz[Cc], wt[Cc], wo[Cc];
  __shared__ float bt, bo, s_zmean, s_izn;
  if (threadIdx.x < Cc) {
    wz[threadIdx.x] = W_sp[24 * Cc + threadIdx.x];
    wt[threadIdx.x] = W_t[threadIdx.x];
    wo[threadIdx.x] = W_o[threadIdx.x];
  }
  if (threadIdx.x == 0) {
    bt = b_t[0];
    bo = b_o[0];
    double sz = red[0], sz2 = red[1], cd = red[2];
    double npos = (cd > 0.0) ? cd : 1.0;
    double zmean = sz / npos;
    double var = sz2 - 2.0 * zmean * sz + cd * zmean * zmean;
    if (var < 0.0) var = 0.0;
    double znorm = sqrt(var) + 1e-5;
    s_zmean = (float)zmean;
    s_izn = (float)(1.0 / znorm);
  }
  __syncthreads();
  int n = blockIdx.x * 256 + threadIdx.x;
  float z = zbuf[n];
  float zn = (z > 0.f) ? (z - s_zmean) * s_izn : 0.f;
  float tsdf = bt, occ = bo;
#pragma unroll
  for (int j = 0; j < Cc; j++) {
    float h = hpartT[j * Npts + n] + zn * wz[j];
    h = fmaxf(h, 0.f);
    tsdf += h * wt[j];
    occ += h * wo[j];
  }
  ((float2*)out)[n] = make_float2(tsdf, occ);
}

// ---------------- launch ---------------------------------------------------
extern "C" void kernel_launch(void* const* d_in, const int* in_sizes, int n_in,
                              void* d_out, int out_size, void* d_ws,
                              size_t ws_size, hipStream_t stream) {
  const float* pre_feat = (const float*)d_in[0];
  const int* pre_coords = (const int*)d_in[1];
  const float* feats = (const float*)d_in[2];
  const float* KRcam = (const float*)d_in[3];
  const float* vol_origin = (const float*)d_in[4];
  const float* w2ac = (const float*)d_in[5];
  const float* W_sp = (const float*)d_in[6];
  const float* b_sp = (const float*)d_in[7];
  const float* W_t = (const float*)d_in[8];
  const float* b_t = (const float*)d_in[9];
  const float* W_o = (const float*)d_in[10];
  const float* b_o = (const float*)d_in[11];

  float* out = (float*)d_out;
  char* ws = (char*)d_ws;
  double* red = (double*)ws;
  float* tf = (float*)(ws + OFF_TF);
  float* pre_h = (float*)(ws + OFF_PREH);
  float* hpartT = (float*)(ws + OFF_HP);
  float* zbuf = (float*)(ws + OFF_Z);

  hipMemsetAsync(red, 0, 32, stream);

  transpose_feats<<<Vv * (PIX / 64), 256, 0, stream>>>(feats, tf);
  pre_h_kernel<<<Mpts / 256, 256, 0, stream>>>(pre_feat, W_sp, b_sp, pre_h);
  main_kernel<<<Npts / 256, 256, 0, stream>>>(pre_coords, tf, KRcam, vol_origin,
                                              w2ac, W_sp, pre_h, out, hpartT,
                                              zbuf, red);
  final_kernel<<<Npts / 256, 256, 0, stream>>>(zbuf, hpartT, W_sp, W_t, b_t,
                                               W_o, b_o, red, out);
}